// Round 1
// baseline (1705.837 us; speedup 1.0000x reference)
//
#include <hip/hip_runtime.h>
#include <math.h>

// Problem constants
#define N_TOK 16384   // B*S
#define DDIM  768
#define HDIM  512
#define KCB   4096

// d_out float offsets (outputs concatenated: quantized_st, loss, perplexity, idx, enc)
#define Q_OFF    0L
#define LOSS_OFF 12582912L
#define PERP_OFF 12582913L
#define IDX_OFF  12582914L
#define ENC_OFF  12599298L

// ---------------------------------------------------------------------------
// init: zero histogram + loss accumulators
__global__ __launch_bounds__(256) void k_init(int* __restrict__ hist, float* __restrict__ sums) {
  int g = blockIdx.x * 256 + threadIdx.x;
  if (g < KCB) hist[g] = 0;
  if (g < 8)   sums[g] = 0.0f;
}

// ---------------------------------------------------------------------------
// latent GEMM: out[M][512] = A[M][768] @ W[512][768]^T + bias[512]
// TM=64 rows, TN=128 cols per block; 256 threads; micro 4x8 per thread.
__global__ __launch_bounds__(256) void k_lat_gemm(const float* __restrict__ A,
                                                  const float* __restrict__ W,
                                                  const float* __restrict__ bias,
                                                  float* __restrict__ out) {
  __shared__ float lds_a[16][64];
  __shared__ float lds_b[16][128];
  const int tid = threadIdx.x;
  const int tx = tid & 15;   // cols: tx*8
  const int ty = tid >> 4;   // rows: ty*4
  const int row0 = blockIdx.y * 64;
  const int col0 = blockIdx.x * 128;
  float ab[4][8];
#pragma unroll
  for (int i = 0; i < 4; ++i)
#pragma unroll
    for (int j = 0; j < 8; ++j) ab[i][j] = 0.0f;

  for (int hb = 0; hb < DDIM; hb += 16) {
    __syncthreads();
    {
      // stage A: 64 rows x 16 h = 256 float4, one per thread
      int r = tid >> 2, h0 = (tid & 3) * 4;
      const float4 v = *(const float4*)&A[(long)(row0 + r) * DDIM + hb + h0];
      lds_a[h0 + 0][r] = v.x; lds_a[h0 + 1][r] = v.y;
      lds_a[h0 + 2][r] = v.z; lds_a[h0 + 3][r] = v.w;
      // stage B: 128 wrows x 16 h = 512 float4, two per thread
#pragma unroll
      for (int i = 0; i < 2; ++i) {
        int u = tid + i * 256;
        int c = u >> 2, hh = (u & 3) * 4;
        const float4 w = *(const float4*)&W[(long)(col0 + c) * DDIM + hb + hh];
        lds_b[hh + 0][c] = w.x; lds_b[hh + 1][c] = w.y;
        lds_b[hh + 2][c] = w.z; lds_b[hh + 3][c] = w.w;
      }
    }
    __syncthreads();
#pragma unroll
    for (int h = 0; h < 16; ++h) {
      const float4 a  = *(const float4*)&lds_a[h][ty * 4];
      const float4 b0 = *(const float4*)&lds_b[h][tx * 8];
      const float4 b1 = *(const float4*)&lds_b[h][tx * 8 + 4];
      const float av[4] = {a.x, a.y, a.z, a.w};
      const float bv[8] = {b0.x, b0.y, b0.z, b0.w, b1.x, b1.y, b1.z, b1.w};
#pragma unroll
      for (int i = 0; i < 4; ++i)
#pragma unroll
        for (int j = 0; j < 8; ++j) ab[i][j] = fmaf(av[i], bv[j], ab[i][j]);
    }
  }
#pragma unroll
  for (int i = 0; i < 4; ++i) {
    const int r = row0 + ty * 4 + i;
    const int c0 = col0 + tx * 8;
    float4 o0, o1;
    o0.x = ab[i][0] + bias[c0 + 0]; o0.y = ab[i][1] + bias[c0 + 1];
    o0.z = ab[i][2] + bias[c0 + 2]; o0.w = ab[i][3] + bias[c0 + 3];
    o1.x = ab[i][4] + bias[c0 + 4]; o1.y = ab[i][5] + bias[c0 + 5];
    o1.z = ab[i][6] + bias[c0 + 6]; o1.w = ab[i][7] + bias[c0 + 7];
    *(float4*)&out[(long)r * HDIM + c0]     = o0;
    *(float4*)&out[(long)r * HDIM + c0 + 4] = o1;
  }
}

// ---------------------------------------------------------------------------
// per-row: inv = 1/sqrt(sum(raw^2)+eps); n2 = sum((raw*inv)^2)   (512 cols)
__global__ __launch_bounds__(64) void k_rownorm(const float* __restrict__ raw,
                                                float* __restrict__ inv,
                                                float* __restrict__ n2) {
  const int row = blockIdx.x;
  const int lane = threadIdx.x;
  const float4 v0 = *(const float4*)&raw[(long)row * HDIM + lane * 8];
  const float4 v1 = *(const float4*)&raw[(long)row * HDIM + lane * 8 + 4];
  float s = v0.x * v0.x + v0.y * v0.y + v0.z * v0.z + v0.w * v0.w
          + v1.x * v1.x + v1.y * v1.y + v1.z * v1.z + v1.w * v1.w;
#pragma unroll
  for (int o = 32; o; o >>= 1) s += __shfl_xor(s, o);
  const float iv = 1.0f / sqrtf(s + 1e-6f);
  float t, s2 = 0.0f;
  t = v0.x * iv; s2 += t * t;  t = v0.y * iv; s2 += t * t;
  t = v0.z * iv; s2 += t * t;  t = v0.w * iv; s2 += t * t;
  t = v1.x * iv; s2 += t * t;  t = v1.y * iv; s2 += t * t;
  t = v1.z * iv; s2 += t * t;  t = v1.w * iv; s2 += t * t;
#pragma unroll
  for (int o = 32; o; o >>= 1) s2 += __shfl_xor(s2, o);
  if (lane == 0) { inv[row] = iv; n2[row] = s2; }
}

// ---------------------------------------------------------------------------
// dist + argmin: per block TM=32 token rows, scan all K codes (TK=256 chunks).
// dist = (a2 - 2*ab) + b2, first-occurrence argmin (matches jnp.argmin).
__global__ __launch_bounds__(256) void k_dist(const float* __restrict__ latin,
                                              const float* __restrict__ inv_a,
                                              const float* __restrict__ a2,
                                              const float* __restrict__ latcb,
                                              const float* __restrict__ inv_b,
                                              const float* __restrict__ b2,
                                              int* __restrict__ idxb,
                                              float* __restrict__ out_idx,
                                              int* __restrict__ hist) {
  __shared__ float lds_a[16][32];
  __shared__ float lds_b[16][256];
  __shared__ float rv[32][33];
  __shared__ int   rk[32][33];
  const int tid = threadIdx.x;
  const int tx = tid & 31;   // cols: tx*8 within chunk
  const int ty = tid >> 5;   // rows: ty*4  (8 -> 32 rows)
  const int row0 = blockIdx.x * 32;

  float bestv[4] = {3.4e38f, 3.4e38f, 3.4e38f, 3.4e38f};
  int   bestk[4] = {0, 0, 0, 0};
  float a2r[4];
#pragma unroll
  for (int i = 0; i < 4; ++i) a2r[i] = a2[row0 + ty * 4 + i];

  for (int kc = 0; kc < KCB; kc += 256) {
    float ab[4][8];
#pragma unroll
    for (int i = 0; i < 4; ++i)
#pragma unroll
      for (int j = 0; j < 8; ++j) ab[i][j] = 0.0f;

    for (int hb = 0; hb < HDIM; hb += 16) {
      __syncthreads();
      if (tid < 128) {  // stage A: 32 rows x 16 h = 128 float4
        int r = tid >> 2, h0 = (tid & 3) * 4;
        const float ivr = inv_a[row0 + r];
        const float4 v = *(const float4*)&latin[(long)(row0 + r) * HDIM + hb + h0];
        lds_a[h0 + 0][r] = v.x * ivr; lds_a[h0 + 1][r] = v.y * ivr;
        lds_a[h0 + 2][r] = v.z * ivr; lds_a[h0 + 3][r] = v.w * ivr;
      }
#pragma unroll
      for (int i = 0; i < 4; ++i) {  // stage B: 256 codes x 16 h = 1024 float4
        int u = tid + i * 256;
        int c = u >> 2, hh = (u & 3) * 4;
        const float ivc = inv_b[kc + c];
        const float4 w = *(const float4*)&latcb[(long)(kc + c) * HDIM + hb + hh];
        lds_b[hh + 0][c] = w.x * ivc; lds_b[hh + 1][c] = w.y * ivc;
        lds_b[hh + 2][c] = w.z * ivc; lds_b[hh + 3][c] = w.w * ivc;
      }
      __syncthreads();
#pragma unroll
      for (int h = 0; h < 16; ++h) {
        const float4 a  = *(const float4*)&lds_a[h][ty * 4];
        const float4 b0 = *(const float4*)&lds_b[h][tx * 8];
        const float4 b1 = *(const float4*)&lds_b[h][tx * 8 + 4];
        const float av[4] = {a.x, a.y, a.z, a.w};
        const float bv[8] = {b0.x, b0.y, b0.z, b0.w, b1.x, b1.y, b1.z, b1.w};
#pragma unroll
        for (int i = 0; i < 4; ++i)
#pragma unroll
          for (int j = 0; j < 8; ++j) ab[i][j] = fmaf(av[i], bv[j], ab[i][j]);
      }
    }
    // finalize this chunk's distances; scan ascending k -> strict '<' keeps first
#pragma unroll
    for (int j = 0; j < 8; ++j) {
      const int c = kc + tx * 8 + j;
      const float b2c = b2[c];
#pragma unroll
      for (int i = 0; i < 4; ++i) {
        const float dd = (a2r[i] - 2.0f * ab[i][j]) + b2c;
        if (dd < bestv[i]) { bestv[i] = dd; bestk[i] = c; }
      }
    }
  }
  __syncthreads();
#pragma unroll
  for (int i = 0; i < 4; ++i) { rv[ty * 4 + i][tx] = bestv[i]; rk[ty * 4 + i][tx] = bestk[i]; }
  __syncthreads();
  if (tid < 32) {
    float bv = rv[tid][0]; int bk = rk[tid][0];
    for (int t = 1; t < 32; ++t) {
      const float v = rv[tid][t]; const int k = rk[tid][t];
      if (v < bv || (v == bv && k < bk)) { bv = v; bk = k; }
    }
    idxb[row0 + tid] = bk;
    out_idx[row0 + tid] = (float)bk;
    atomicAdd(&hist[bk], 1);
  }
}

// ---------------------------------------------------------------------------
// quantized_st = x + (q - x); accumulate sum((q-x)^2) into sums[0]
__global__ __launch_bounds__(256) void k_quant_m1(const float* __restrict__ x,
                                                  const float* __restrict__ cb,
                                                  const int* __restrict__ idxb,
                                                  float* __restrict__ outq,
                                                  float* __restrict__ sums) {
  const long u = (long)blockIdx.x * 256 + threadIdx.x;
  const int n = (int)(u / 192);
  const int d = ((int)(u % 192)) * 4;
  const float4 xv = *(const float4*)&x[(long)n * DDIM + d];
  const int k = idxb[n];
  const float4 qv = *(const float4*)&cb[(long)k * DDIM + d];
  const float dx0 = qv.x - xv.x, dx1 = qv.y - xv.y, dx2 = qv.z - xv.z, dx3 = qv.w - xv.w;
  float4 o;
  o.x = xv.x + dx0; o.y = xv.y + dx1; o.z = xv.z + dx2; o.w = xv.w + dx3;
  *(float4*)&outq[(long)n * DDIM + d] = o;
  float lsum = dx0 * dx0 + dx1 * dx1 + dx2 * dx2 + dx3 * dx3;
  __shared__ float red[256];
  const int tid = threadIdx.x;
  red[tid] = lsum; __syncthreads();
  for (int s = 128; s; s >>= 1) { if (tid < s) red[tid] += red[tid + s]; __syncthreads(); }
  if (tid == 0) atomicAdd(&sums[0], red[0]);
}

// latent-space loss: sum((latcb_raw[idx[n]] - latin_raw[n])^2) into sums[1]
__global__ __launch_bounds__(256) void k_m2(const float* __restrict__ latin,
                                            const float* __restrict__ latcb,
                                            const int* __restrict__ idxb,
                                            float* __restrict__ sums) {
  const long u = (long)blockIdx.x * 256 + threadIdx.x;
  const int n = (int)(u / 128);
  const int h = ((int)(u % 128)) * 4;
  const int k = idxb[n];
  const float4 lq = *(const float4*)&latcb[(long)k * HDIM + h];
  const float4 lx = *(const float4*)&latin[(long)n * HDIM + h];
  const float d0 = lq.x - lx.x, d1 = lq.y - lx.y, d2 = lq.z - lx.z, d3 = lq.w - lx.w;
  float lsum = d0 * d0 + d1 * d1 + d2 * d2 + d3 * d3;
  __shared__ float red[256];
  const int tid = threadIdx.x;
  red[tid] = lsum; __syncthreads();
  for (int s = 128; s; s >>= 1) { if (tid < s) red[tid] += red[tid + s]; __syncthreads(); }
  if (tid == 0) atomicAdd(&sums[1], red[0]);
}

// one-hot enc write (full 256 MB every call)
__global__ __launch_bounds__(256) void k_enc(const int* __restrict__ idxb,
                                             float* __restrict__ enc) {
  const long u = (long)blockIdx.x * 256 + threadIdx.x;
  const int n = (int)(u >> 10);
  const int c0 = ((int)(u & 1023)) << 2;
  const int k = idxb[n];
  float4 e;
  e.x = (c0     == k) ? 1.0f : 0.0f;
  e.y = (c0 + 1 == k) ? 1.0f : 0.0f;
  e.z = (c0 + 2 == k) ? 1.0f : 0.0f;
  e.w = (c0 + 3 == k) ? 1.0f : 0.0f;
  *(float4*)&enc[u << 2] = e;
}

// perplexity + final loss
__global__ __launch_bounds__(256) void k_finalize(const int* __restrict__ hist,
                                                  const float* __restrict__ sums,
                                                  float* __restrict__ out) {
  const int tid = threadIdx.x;
  float lsum = 0.0f;
  for (int i = tid; i < KCB; i += 256) {
    const float p = (float)hist[i] * (1.0f / 16384.0f);
    lsum += p * logf(p + 1e-6f);
  }
  __shared__ float red[256];
  red[tid] = lsum; __syncthreads();
  for (int s = 128; s; s >>= 1) { if (tid < s) red[tid] += red[tid + s]; __syncthreads(); }
  if (tid == 0) {
    const float lp = -red[0];
    const float m1 = sums[0] / 12582912.0f;  // mean over N*D
    const float m2 = sums[1] / 8388608.0f;   // mean over N*H
    const float e1 = m1 * 0.25f, q1 = m1, e2 = m2 * 0.25f, q2 = m2;
    out[LOSS_OFF] = e1 + q1 + e2 + q2 + 0.1f * lp;
    out[PERP_OFF] = expf(lp);
  }
}

// ---------------------------------------------------------------------------
extern "C" void kernel_launch(void* const* d_in, const int* in_sizes, int n_in,
                              void* d_out, int out_size, void* d_ws, size_t ws_size,
                              hipStream_t stream) {
  const float* x      = (const float*)d_in[0];
  const float* cb     = (const float*)d_in[1];
  const float* w_in   = (const float*)d_in[2];
  const float* b_in   = (const float*)d_in[3];
  const float* w_code = (const float*)d_in[4];
  const float* b_code = (const float*)d_in[5];
  float* out = (float*)d_out;
  char* ws = (char*)d_ws;

  float* latcb = (float*)(ws);                 // 4096*512 f32  (8 MB)
  float* latin = (float*)(ws + 8388608);       // 16384*512 f32 (32 MB)
  float* inv_b = (float*)(ws + 41943040);      // 4096 f32
  float* b2    = (float*)(ws + 41959424);      // 4096 f32
  float* inv_a = (float*)(ws + 41975808);      // 16384 f32
  float* a2    = (float*)(ws + 42041344);      // 16384 f32
  int*   idxb  = (int*)  (ws + 42106880);      // 16384 i32
  int*   hist  = (int*)  (ws + 42172416);      // 4096 i32
  float* sums  = (float*)(ws + 42188800);      // 8 f32

  k_init<<<16, 256, 0, stream>>>(hist, sums);
  k_lat_gemm<<<dim3(4, KCB / 64),  256, 0, stream>>>(cb, w_code, b_code, latcb);
  k_lat_gemm<<<dim3(4, N_TOK / 64), 256, 0, stream>>>(x, w_in, b_in, latin);
  k_rownorm<<<KCB,   64, 0, stream>>>(latcb, inv_b, b2);
  k_rownorm<<<N_TOK, 64, 0, stream>>>(latin, inv_a, a2);
  k_dist<<<N_TOK / 32, 256, 0, stream>>>(latin, inv_a, a2, latcb, inv_b, b2,
                                         idxb, out + IDX_OFF, hist);
  k_quant_m1<<<(N_TOK * (DDIM / 4)) / 256, 256, 0, stream>>>(x, cb, idxb, out + Q_OFF, sums);
  k_m2<<<(N_TOK * (HDIM / 4)) / 256, 256, 0, stream>>>(latin, latcb, idxb, sums);
  k_enc<<<(N_TOK * (KCB / 4)) / 256, 256, 0, stream>>>(idxb, out + ENC_OFF);
  k_finalize<<<1, 256, 0, stream>>>(hist, sums, out);
}

// Round 2
// 823.468 us; speedup vs baseline: 2.0715x; 2.0715x over previous
//
#include <hip/hip_runtime.h>
#include <math.h>

// Problem constants
#define N_TOK 16384   // B*S
#define DDIM  768
#define HDIM  512
#define KCB   4096

// d_out float offsets (outputs concatenated: quantized_st, loss, perplexity, idx, enc)
#define Q_OFF    0L
#define LOSS_OFF 12582912L
#define PERP_OFF 12582913L
#define IDX_OFF  12582914L
#define ENC_OFF  12599298L

// dist-screen geometry
#define BM 64
#define BN 256
#define NSPLIT 2
#define CODES_PER (KCB / NSPLIT)   // 2048
#define NCHUNK (CODES_PER / BN)    // 8
#define NSTEP (NCHUNK * 16)        // 128 K-steps (HDIM/32 = 16 per chunk)
#define MARGIN_AB 4.0e-3f          // >> 2*max bf16 dot error (~6e-4)
#define CAND_CAP 128

typedef short bf16x8 __attribute__((ext_vector_type(8)));
typedef float f32x4  __attribute__((ext_vector_type(4)));

__device__ __forceinline__ void gload_lds16(const void* g, void* l) {
  __builtin_amdgcn_global_load_lds((const __attribute__((address_space(1))) void*)g,
                                   (__attribute__((address_space(3))) void*)l, 16, 0, 0);
}

__device__ __forceinline__ unsigned short f2bf(float f) {  // RNE f32 -> bf16
  unsigned u = __float_as_uint(f);
  return (unsigned short)((u + 0x7fffu + ((u >> 16) & 1u)) >> 16);
}

// ---------------------------------------------------------------------------
// init: zero histogram + loss accumulators + candidate counters
__global__ __launch_bounds__(256) void k_init(int* __restrict__ hist, float* __restrict__ sums,
                                              int* __restrict__ g_cnt) {
  int g = blockIdx.x * 256 + threadIdx.x;
  if (g < N_TOK) g_cnt[g] = 0;
  if (g < KCB)  hist[g] = 0;
  if (g < 8)    sums[g] = 0.0f;
}

// ---------------------------------------------------------------------------
// latent GEMM: out[M][512] = A[M][768] @ W[512][768]^T + bias[512]  (fp32)
__global__ __launch_bounds__(256) void k_lat_gemm(const float* __restrict__ A,
                                                  const float* __restrict__ W,
                                                  const float* __restrict__ bias,
                                                  float* __restrict__ out) {
  __shared__ float lds_a[16][64];
  __shared__ float lds_b[16][128];
  const int tid = threadIdx.x;
  const int tx = tid & 15;
  const int ty = tid >> 4;
  const int row0 = blockIdx.y * 64;
  const int col0 = blockIdx.x * 128;
  float ab[4][8];
#pragma unroll
  for (int i = 0; i < 4; ++i)
#pragma unroll
    for (int j = 0; j < 8; ++j) ab[i][j] = 0.0f;

  for (int hb = 0; hb < DDIM; hb += 16) {
    __syncthreads();
    {
      int r = tid >> 2, h0 = (tid & 3) * 4;
      const float4 v = *(const float4*)&A[(long)(row0 + r) * DDIM + hb + h0];
      lds_a[h0 + 0][r] = v.x; lds_a[h0 + 1][r] = v.y;
      lds_a[h0 + 2][r] = v.z; lds_a[h0 + 3][r] = v.w;
#pragma unroll
      for (int i = 0; i < 2; ++i) {
        int u = tid + i * 256;
        int c = u >> 2, hh = (u & 3) * 4;
        const float4 w = *(const float4*)&W[(long)(col0 + c) * DDIM + hb + hh];
        lds_b[hh + 0][c] = w.x; lds_b[hh + 1][c] = w.y;
        lds_b[hh + 2][c] = w.z; lds_b[hh + 3][c] = w.w;
      }
    }
    __syncthreads();
#pragma unroll
    for (int h = 0; h < 16; ++h) {
      const float4 a  = *(const float4*)&lds_a[h][ty * 4];
      const float4 b0 = *(const float4*)&lds_b[h][tx * 8];
      const float4 b1 = *(const float4*)&lds_b[h][tx * 8 + 4];
      const float av[4] = {a.x, a.y, a.z, a.w};
      const float bv[8] = {b0.x, b0.y, b0.z, b0.w, b1.x, b1.y, b1.z, b1.w};
#pragma unroll
      for (int i = 0; i < 4; ++i)
#pragma unroll
        for (int j = 0; j < 8; ++j) ab[i][j] = fmaf(av[i], bv[j], ab[i][j]);
    }
  }
#pragma unroll
  for (int i = 0; i < 4; ++i) {
    const int r = row0 + ty * 4 + i;
    const int c0 = col0 + tx * 8;
    float4 o0, o1;
    o0.x = ab[i][0] + bias[c0 + 0]; o0.y = ab[i][1] + bias[c0 + 1];
    o0.z = ab[i][2] + bias[c0 + 2]; o0.w = ab[i][3] + bias[c0 + 3];
    o1.x = ab[i][4] + bias[c0 + 4]; o1.y = ab[i][5] + bias[c0 + 5];
    o1.z = ab[i][6] + bias[c0 + 6]; o1.w = ab[i][7] + bias[c0 + 7];
    *(float4*)&out[(long)r * HDIM + c0]     = o0;
    *(float4*)&out[(long)r * HDIM + c0 + 4] = o1;
  }
}

// ---------------------------------------------------------------------------
// per-row: inv = 1/sqrt(sum(raw^2)+eps); n2 = sum((raw*inv)^2); bf16 normalized row
__global__ __launch_bounds__(64) void k_rownorm(const float* __restrict__ raw,
                                                float* __restrict__ inv,
                                                float* __restrict__ n2,
                                                unsigned short* __restrict__ nbf) {
  const int row = blockIdx.x;
  const int lane = threadIdx.x;
  const float4 v0 = *(const float4*)&raw[(long)row * HDIM + lane * 8];
  const float4 v1 = *(const float4*)&raw[(long)row * HDIM + lane * 8 + 4];
  float s = v0.x * v0.x + v0.y * v0.y + v0.z * v0.z + v0.w * v0.w
          + v1.x * v1.x + v1.y * v1.y + v1.z * v1.z + v1.w * v1.w;
#pragma unroll
  for (int o = 32; o; o >>= 1) s += __shfl_xor(s, o);
  const float iv = 1.0f / sqrtf(s + 1e-6f);
  float t[8];
  t[0] = v0.x * iv; t[1] = v0.y * iv; t[2] = v0.z * iv; t[3] = v0.w * iv;
  t[4] = v1.x * iv; t[5] = v1.y * iv; t[6] = v1.z * iv; t[7] = v1.w * iv;
  float s2 = 0.0f;
#pragma unroll
  for (int j = 0; j < 8; ++j) s2 += t[j] * t[j];
#pragma unroll
  for (int o = 32; o; o >>= 1) s2 += __shfl_xor(s2, o);
  bf16x8 pk;
#pragma unroll
  for (int j = 0; j < 8; ++j) pk[j] = (short)f2bf(t[j]);
  *(bf16x8*)&nbf[(long)row * HDIM + lane * 8] = pk;
  if (lane == 0) { inv[row] = iv; n2[row] = s2; }
}

// ---------------------------------------------------------------------------
// bf16 MFMA screening: per row, collect candidate codes with ab >= max - margin.
// Block: 64 rows x 2048 codes (blockIdx.y half), chunks of 256 codes, K=512 in 32-steps.
__global__ __launch_bounds__(256) void k_dist_screen(const unsigned short* __restrict__ Abf,
                                                     const unsigned short* __restrict__ Bbf,
                                                     int* __restrict__ g_cnt,
                                                     int* __restrict__ g_cand) {
  __shared__ __align__(16) unsigned short A_lds[2][BM][32];
  __shared__ __align__(16) unsigned short B_lds[2][BN][32];

  const int tid = threadIdx.x;
  const int lane = tid & 63;
  const int w = tid >> 6;
  const int wr = w >> 1, wc = w & 1;     // wave tile: 32 rows x 128 codes
  const int row0 = blockIdx.x * BM;
  const int csplit = blockIdx.y * CODES_PER;
  const int wbase = tid & ~63;

  f32x4 acc[2][8];
#pragma unroll
  for (int mi = 0; mi < 2; ++mi)
#pragma unroll
    for (int nj = 0; nj < 8; ++nj)
#pragma unroll
      for (int r = 0; r < 4; ++r) acc[mi][nj][r] = 0.0f;

  float runmax[8];
#pragma unroll
  for (int i = 0; i < 8; ++i) runmax[i] = -3.0e38f;

  // stage step s into buffer b: A 256x16B + B 1024x16B, linear LDS dests
#define STAGE(s_, b_)                                                              \
  do {                                                                             \
    const int chunk_ = (s_) >> 4, kk_ = (s_) & 15;                                 \
    const long kel_ = (long)(kk_ * 32);                                            \
    {                                                                              \
      const int r_ = tid >> 2, seg_ = tid & 3;                                     \
      const unsigned short* g_ = &Abf[(long)(row0 + r_) * HDIM + kel_ + seg_ * 8]; \
      void* l_ = (char*)&A_lds[b_][0][0] + (size_t)wbase * 16;                     \
      gload_lds16(g_, l_);                                                         \
    }                                                                              \
    const int c0_ = csplit + chunk_ * BN;                                          \
    _Pragma("unroll")                                                              \
    for (int i_ = 0; i_ < 4; ++i_) {                                               \
      const int u_ = tid + i_ * 256;                                               \
      const int r_ = u_ >> 2, seg_ = u_ & 3;                                       \
      const unsigned short* g_ = &Bbf[(long)(c0_ + r_) * HDIM + kel_ + seg_ * 8];  \
      void* l_ = (char*)&B_lds[b_][0][0] + (size_t)(i_ * 256 + wbase) * 16;        \
      gload_lds16(g_, l_);                                                         \
    }                                                                              \
  } while (0)

  STAGE(0, 0);
  __syncthreads();

  const int arow = lane & 15;
  const int kcol = (lane >> 4) * 8;
  const int rgrp = (lane >> 4) * 4;

  for (int s = 0; s < NSTEP; ++s) {
    const int b = s & 1;
    if (s + 1 < NSTEP) STAGE(s + 1, b ^ 1);

    bf16x8 af[2], bfr[8];
#pragma unroll
    for (int mi = 0; mi < 2; ++mi)
      af[mi] = *(const bf16x8*)&A_lds[b][wr * 32 + mi * 16 + arow][kcol];
#pragma unroll
    for (int nj = 0; nj < 8; ++nj)
      bfr[nj] = *(const bf16x8*)&B_lds[b][wc * 128 + nj * 16 + arow][kcol];
#pragma unroll
    for (int mi = 0; mi < 2; ++mi)
#pragma unroll
      for (int nj = 0; nj < 8; ++nj)
        acc[mi][nj] = __builtin_amdgcn_mfma_f32_16x16x32_bf16(af[mi], bfr[nj], acc[mi][nj], 0, 0, 0);

    if ((s & 15) == 15) {  // chunk epilogue: screening
      const int chunk = s >> 4;
      const int cbase = csplit + chunk * BN + wc * 128;
      // 1) per-slot max over this lane's values
      float slotmax[8];
#pragma unroll
      for (int mi = 0; mi < 2; ++mi)
#pragma unroll
        for (int r = 0; r < 4; ++r) {
          float m = acc[mi][0][r];
#pragma unroll
          for (int nj = 1; nj < 8; ++nj) m = fmaxf(m, acc[mi][nj][r]);
          slotmax[mi * 4 + r] = m;
        }
      // 2) butterfly max across the 16-lane group sharing these rows
#pragma unroll
      for (int d = 1; d < 16; d <<= 1)
#pragma unroll
        for (int sl = 0; sl < 8; ++sl)
          slotmax[sl] = fmaxf(slotmax[sl], __shfl_xor(slotmax[sl], d));
      // 3) update running max
#pragma unroll
      for (int sl = 0; sl < 8; ++sl) runmax[sl] = fmaxf(runmax[sl], slotmax[sl]);
      // 4) insert candidates above threshold
#pragma unroll
      for (int mi = 0; mi < 2; ++mi)
#pragma unroll
        for (int r = 0; r < 4; ++r) {
          const float th = runmax[mi * 4 + r] - MARGIN_AB;
          const int grow = row0 + wr * 32 + mi * 16 + rgrp + r;
#pragma unroll
          for (int nj = 0; nj < 8; ++nj) {
            const float ab = acc[mi][nj][r];
            if (ab > th) {
              const int c = cbase + nj * 16 + arow;
              const int p = atomicAdd(&g_cnt[grow], 1);
              if (p < CAND_CAP) g_cand[(long)grow * CAND_CAP + p] = c;
            }
            acc[mi][nj][r] = 0.0f;
          }
        }
    }
    __syncthreads();
  }
#undef STAGE
}

// ---------------------------------------------------------------------------
// exact fp32 rescore of candidates; first-occurrence (smallest code) tie-break
__global__ __launch_bounds__(256) void k_rescore(const float* __restrict__ latin,
                                                 const float* __restrict__ inv_a,
                                                 const float* __restrict__ a2,
                                                 const float* __restrict__ latcb,
                                                 const float* __restrict__ inv_b,
                                                 const float* __restrict__ b2,
                                                 const int* __restrict__ g_cnt,
                                                 const int* __restrict__ g_cand,
                                                 int* __restrict__ idxb,
                                                 float* __restrict__ out_idx,
                                                 int* __restrict__ hist) {
  const int tid = threadIdx.x;
  const int lane = tid & 63;
  const int row = blockIdx.x * 4 + (tid >> 6);
  const float iva = inv_a[row];
  const float4 v0 = *(const float4*)&latin[(long)row * HDIM + lane * 8];
  const float4 v1 = *(const float4*)&latin[(long)row * HDIM + lane * 8 + 4];
  float na[8];
  na[0] = v0.x * iva; na[1] = v0.y * iva; na[2] = v0.z * iva; na[3] = v0.w * iva;
  na[4] = v1.x * iva; na[5] = v1.y * iva; na[6] = v1.z * iva; na[7] = v1.w * iva;
  const float a2r = a2[row];
  int cnt = g_cnt[row]; if (cnt > CAND_CAP) cnt = CAND_CAP;
  float best = 3.4e38f; int bestc = 0x7fffffff;
  for (int ci = 0; ci < cnt; ++ci) {
    const int c = g_cand[(long)row * CAND_CAP + ci];
    const float ivb = inv_b[c];
    const float4 w0 = *(const float4*)&latcb[(long)c * HDIM + lane * 8];
    const float4 w1 = *(const float4*)&latcb[(long)c * HDIM + lane * 8 + 4];
    float dot = 0.0f;
    dot = fmaf(na[0], w0.x * ivb, dot); dot = fmaf(na[1], w0.y * ivb, dot);
    dot = fmaf(na[2], w0.z * ivb, dot); dot = fmaf(na[3], w0.w * ivb, dot);
    dot = fmaf(na[4], w1.x * ivb, dot); dot = fmaf(na[5], w1.y * ivb, dot);
    dot = fmaf(na[6], w1.z * ivb, dot); dot = fmaf(na[7], w1.w * ivb, dot);
#pragma unroll
    for (int o = 32; o; o >>= 1) dot += __shfl_xor(dot, o);
    const float dist = (a2r - 2.0f * dot) + b2[c];
    if (dist < best || (dist == best && c < bestc)) { best = dist; bestc = c; }
  }
  if (lane == 0) {
    idxb[row] = bestc;
    out_idx[row] = (float)bestc;
    atomicAdd(&hist[bestc], 1);
  }
}

// ---------------------------------------------------------------------------
// quantized_st = x + (q - x); accumulate sum((q-x)^2) into sums[0]
__global__ __launch_bounds__(256) void k_quant_m1(const float* __restrict__ x,
                                                  const float* __restrict__ cb,
                                                  const int* __restrict__ idxb,
                                                  float* __restrict__ outq,
                                                  float* __restrict__ sums) {
  const long u = (long)blockIdx.x * 256 + threadIdx.x;
  const int n = (int)(u / 192);
  const int d = ((int)(u % 192)) * 4;
  const float4 xv = *(const float4*)&x[(long)n * DDIM + d];
  const int k = idxb[n];
  const float4 qv = *(const float4*)&cb[(long)k * DDIM + d];
  const float dx0 = qv.x - xv.x, dx1 = qv.y - xv.y, dx2 = qv.z - xv.z, dx3 = qv.w - xv.w;
  float4 o;
  o.x = xv.x + dx0; o.y = xv.y + dx1; o.z = xv.z + dx2; o.w = xv.w + dx3;
  *(float4*)&outq[(long)n * DDIM + d] = o;
  float lsum = dx0 * dx0 + dx1 * dx1 + dx2 * dx2 + dx3 * dx3;
  __shared__ float red[256];
  const int tid = threadIdx.x;
  red[tid] = lsum; __syncthreads();
  for (int s = 128; s; s >>= 1) { if (tid < s) red[tid] += red[tid + s]; __syncthreads(); }
  if (tid == 0) atomicAdd(&sums[0], red[0]);
}

// latent-space loss: sum((latcb_raw[idx[n]] - latin_raw[n])^2) into sums[1]
__global__ __launch_bounds__(256) void k_m2(const float* __restrict__ latin,
                                            const float* __restrict__ latcb,
                                            const int* __restrict__ idxb,
                                            float* __restrict__ sums) {
  const long u = (long)blockIdx.x * 256 + threadIdx.x;
  const int n = (int)(u / 128);
  const int h = ((int)(u % 128)) * 4;
  const int k = idxb[n];
  const float4 lq = *(const float4*)&latcb[(long)k * HDIM + h];
  const float4 lx = *(const float4*)&latin[(long)n * HDIM + h];
  const float d0 = lq.x - lx.x, d1 = lq.y - lx.y, d2 = lq.z - lx.z, d3 = lq.w - lx.w;
  float lsum = d0 * d0 + d1 * d1 + d2 * d2 + d3 * d3;
  __shared__ float red[256];
  const int tid = threadIdx.x;
  red[tid] = lsum; __syncthreads();
  for (int s = 128; s; s >>= 1) { if (tid < s) red[tid] += red[tid + s]; __syncthreads(); }
  if (tid == 0) atomicAdd(&sums[1], red[0]);
}

// one-hot enc write
__global__ __launch_bounds__(256) void k_enc(const int* __restrict__ idxb,
                                             float* __restrict__ enc) {
  const long u = (long)blockIdx.x * 256 + threadIdx.x;
  const int n = (int)(u >> 10);
  const int c0 = ((int)(u & 1023)) << 2;
  const int k = idxb[n];
  float4 e;
  e.x = (c0     == k) ? 1.0f : 0.0f;
  e.y = (c0 + 1 == k) ? 1.0f : 0.0f;
  e.z = (c0 + 2 == k) ? 1.0f : 0.0f;
  e.w = (c0 + 3 == k) ? 1.0f : 0.0f;
  *(float4*)&enc[u << 2] = e;
}

// perplexity + final loss
__global__ __launch_bounds__(256) void k_finalize(const int* __restrict__ hist,
                                                  const float* __restrict__ sums,
                                                  float* __restrict__ out) {
  const int tid = threadIdx.x;
  float lsum = 0.0f;
  for (int i = tid; i < KCB; i += 256) {
    const float p = (float)hist[i] * (1.0f / 16384.0f);
    lsum += p * logf(p + 1e-6f);
  }
  __shared__ float red[256];
  red[tid] = lsum; __syncthreads();
  for (int s = 128; s; s >>= 1) { if (tid < s) red[tid] += red[tid + s]; __syncthreads(); }
  if (tid == 0) {
    const float lp = -red[0];
    const float m1 = sums[0] / 12582912.0f;
    const float m2 = sums[1] / 8388608.0f;
    out[LOSS_OFF] = m1 * 1.25f + m2 * 1.25f + 0.1f * lp;
    out[PERP_OFF] = expf(lp);
  }
}

// ---------------------------------------------------------------------------
extern "C" void kernel_launch(void* const* d_in, const int* in_sizes, int n_in,
                              void* d_out, int out_size, void* d_ws, size_t ws_size,
                              hipStream_t stream) {
  const float* x      = (const float*)d_in[0];
  const float* cb     = (const float*)d_in[1];
  const float* w_in   = (const float*)d_in[2];
  const float* b_in   = (const float*)d_in[3];
  const float* w_code = (const float*)d_in[4];
  const float* b_code = (const float*)d_in[5];
  float* out = (float*)d_out;
  char* ws = (char*)d_ws;

  float*          latcb    = (float*)(ws);                      // 8 MB
  float*          latin    = (float*)(ws + 8388608);            // 32 MB
  unsigned short* latcb_bf = (unsigned short*)(ws + 41943040);  // 4 MB
  unsigned short* latin_bf = (unsigned short*)(ws + 46137344);  // 16 MB
  float*          inv_b    = (float*)(ws + 62914560);
  float*          b2       = (float*)(ws + 62930944);
  float*          inv_a    = (float*)(ws + 62947328);
  float*          a2       = (float*)(ws + 63012864);
  int*            idxb     = (int*)  (ws + 63078400);
  int*            hist     = (int*)  (ws + 63143936);
  float*          sums     = (float*)(ws + 63160320);
  int*            g_cnt    = (int*)  (ws + 63160352);
  int*            g_cand   = (int*)  (ws + 63225888);           // 8 MB

  k_init<<<64, 256, 0, stream>>>(hist, sums, g_cnt);
  k_lat_gemm<<<dim3(4, KCB / 64),   256, 0, stream>>>(cb, w_code, b_code, latcb);
  k_lat_gemm<<<dim3(4, N_TOK / 64), 256, 0, stream>>>(x, w_in, b_in, latin);
  k_rownorm<<<KCB,   64, 0, stream>>>(latcb, inv_b, b2, latcb_bf);
  k_rownorm<<<N_TOK, 64, 0, stream>>>(latin, inv_a, a2, latin_bf);
  k_dist_screen<<<dim3(N_TOK / BM, NSPLIT), 256, 0, stream>>>(latin_bf, latcb_bf, g_cnt, g_cand);
  k_rescore<<<N_TOK / 4, 256, 0, stream>>>(latin, inv_a, a2, latcb, inv_b, b2,
                                           g_cnt, g_cand, idxb, out + IDX_OFF, hist);
  k_quant_m1<<<(N_TOK * (DDIM / 4)) / 256, 256, 0, stream>>>(x, cb, idxb, out + Q_OFF, sums);
  k_m2<<<(N_TOK * (HDIM / 4)) / 256, 256, 0, stream>>>(latin, latcb, idxb, sums);
  k_enc<<<(N_TOK * (KCB / 4)) / 256, 256, 0, stream>>>(idxb, out + ENC_OFF);
  k_finalize<<<1, 256, 0, stream>>>(hist, sums, out);
}

// Round 3
// 717.994 us; speedup vs baseline: 2.3758x; 1.1469x over previous
//
#include <hip/hip_runtime.h>
#include <math.h>

// Problem constants
#define N_TOK 16384   // B*S
#define DDIM  768
#define HDIM  512
#define KCB   4096

// d_out float offsets (outputs concatenated: quantized_st, loss, perplexity, idx, enc)
#define Q_OFF    0L
#define LOSS_OFF 12582912L
#define PERP_OFF 12582913L
#define IDX_OFF  12582914L
#define ENC_OFF  12599298L

// dist-screen geometry
#define BM 64
#define BN 256
#define NSPLIT 4
#define CODES_PER (KCB / NSPLIT)   // 1024
#define NCHUNK (CODES_PER / BN)    // 4
#define NSTEP (NCHUNK * 16)        // 64 K-steps (HDIM/32 = 16 per chunk)
#define MARGIN_AB 4.0e-3f          // >> 2*max bf16 dot error (~6e-4)
#define CAND_CAP 128

// hgemm geometry: K' = 2304 (Ah@Wh | Al@Wh | Ah@Wl), stored as [Ah|Al] (1536) / [Wh|Wl]
#define KP 2304
#define KS 1536
#define HSTEPS (KP / 32)   // 72

typedef short    bf16x8 __attribute__((ext_vector_type(8)));
typedef _Float16 half8  __attribute__((ext_vector_type(8)));
typedef float    f32x4  __attribute__((ext_vector_type(4)));

__device__ __forceinline__ void gload_lds16(const void* g, void* l) {
  __builtin_amdgcn_global_load_lds((const __attribute__((address_space(1))) void*)g,
                                   (__attribute__((address_space(3))) void*)l, 16, 0, 0);
}

__device__ __forceinline__ unsigned short f2bf(float f) {  // RNE f32 -> bf16
  unsigned u = __float_as_uint(f);
  return (unsigned short)((u + 0x7fffu + ((u >> 16) & 1u)) >> 16);
}

// ---------------------------------------------------------------------------
__global__ __launch_bounds__(256) void k_init(int* __restrict__ hist, float* __restrict__ sums,
                                              int* __restrict__ g_cnt) {
  int g = blockIdx.x * 256 + threadIdx.x;
  if (g < N_TOK) g_cnt[g] = 0;
  if (g < KCB)  hist[g] = 0;
  if (g < 8)    sums[g] = 0.0f;
}

// ---------------------------------------------------------------------------
// fp32 [M][768] -> fp16 hi/lo [M][1536] = [hi(768) | lo(768)]
__global__ __launch_bounds__(256) void k_split(const float* __restrict__ src,
                                               _Float16* __restrict__ dst) {
  const long u = (long)blockIdx.x * 256 + threadIdx.x;
  const long n = u / 96;
  const int  c0 = ((int)(u % 96)) * 8;
  const float4 v0 = *(const float4*)&src[n * DDIM + c0];
  const float4 v1 = *(const float4*)&src[n * DDIM + c0 + 4];
  const float f[8] = {v0.x, v0.y, v0.z, v0.w, v1.x, v1.y, v1.z, v1.w};
  half8 hv, lv;
#pragma unroll
  for (int j = 0; j < 8; ++j) {
    const _Float16 h = (_Float16)f[j];
    hv[j] = h;
    lv[j] = (_Float16)(f[j] - (float)h);
  }
  *(half8*)&dst[n * KS + c0]       = hv;
  *(half8*)&dst[n * KS + 768 + c0] = lv;
}

// ---------------------------------------------------------------------------
// fp16 split MFMA GEMM: out[M][512] = A[M][768]@W[512][768]^T + bias.
// Fused launch: bx<256 -> x-gemm, else codebook-gemm. BM=64, BN=256, 72 K-steps.
__global__ __launch_bounds__(256) void k_hgemm(const _Float16* __restrict__ x2,
                                               const _Float16* __restrict__ cb2,
                                               const _Float16* __restrict__ win2,
                                               const _Float16* __restrict__ wcode2,
                                               const float* __restrict__ b_in,
                                               const float* __restrict__ b_code,
                                               float* __restrict__ latin,
                                               float* __restrict__ latcb) {
  __shared__ __align__(16) _Float16 A_lds[2][BM][32];
  __shared__ __align__(16) _Float16 B_lds[2][BN][32];

  const int tid = threadIdx.x;
  const int lane = tid & 63;
  const int w = tid >> 6;
  const int wr = w >> 1, wc = w & 1;   // wave tile: 32 rows x 128 cols
  const int bx = blockIdx.x;
  const int col0 = blockIdx.y * BN;

  const _Float16* Ap; const _Float16* Bp; const float* biasp; float* outp; int row0;
  if (bx < 256) { Ap = x2;  Bp = win2;   biasp = b_in;   outp = latin; row0 = bx * BM; }
  else          { Ap = cb2; Bp = wcode2; biasp = b_code; outp = latcb; row0 = (bx - 256) * BM; }

  f32x4 acc[2][8];
#pragma unroll
  for (int mi = 0; mi < 2; ++mi)
#pragma unroll
    for (int nj = 0; nj < 8; ++nj)
#pragma unroll
      for (int r = 0; r < 4; ++r) acc[mi][nj][r] = 0.0f;

#define HSTAGE(s_, b_)                                                         \
  do {                                                                         \
    const int kel_ = (s_) * 32;                                                \
    const int kA_ = (kel_ < KS) ? kel_ : (kel_ - KS);                          \
    const int kB_ = (kel_ < 768) ? kel_ : (kel_ - 768);                        \
    {                                                                          \
      const int r_ = tid >> 2, seg_ = tid & 3;                                 \
      const _Float16* g_ = &Ap[(long)(row0 + r_) * KS + kA_ + seg_ * 8];       \
      gload_lds16(g_, (char*)&A_lds[b_][0][0] + (size_t)tid * 16);             \
    }                                                                          \
    _Pragma("unroll")                                                          \
    for (int i_ = 0; i_ < 4; ++i_) {                                           \
      const int u_ = tid + i_ * 256;                                           \
      const int r_ = u_ >> 2, seg_ = u_ & 3;                                   \
      const _Float16* g_ = &Bp[(long)(col0 + r_) * KS + kB_ + seg_ * 8];       \
      gload_lds16(g_, (char*)&B_lds[b_][0][0] + (size_t)u_ * 16);              \
    }                                                                          \
  } while (0)

  HSTAGE(0, 0);
  __syncthreads();

  const int arow = lane & 15;
  const int kcol = (lane >> 4) * 8;

  for (int s = 0; s < HSTEPS; ++s) {
    const int b = s & 1;
    if (s + 1 < HSTEPS) HSTAGE(s + 1, b ^ 1);
    half8 af[2], bfr[8];
#pragma unroll
    for (int mi = 0; mi < 2; ++mi)
      af[mi] = *(const half8*)&A_lds[b][wr * 32 + mi * 16 + arow][kcol];
#pragma unroll
    for (int nj = 0; nj < 8; ++nj)
      bfr[nj] = *(const half8*)&B_lds[b][wc * 128 + nj * 16 + arow][kcol];
#pragma unroll
    for (int mi = 0; mi < 2; ++mi)
#pragma unroll
      for (int nj = 0; nj < 8; ++nj)
        acc[mi][nj] = __builtin_amdgcn_mfma_f32_16x16x32_f16(af[mi], bfr[nj], acc[mi][nj], 0, 0, 0);
    __syncthreads();
  }
#undef HSTAGE

  const int rgrp = (lane >> 4) * 4;
#pragma unroll
  for (int nj = 0; nj < 8; ++nj) {
    const int ocol = col0 + wc * 128 + nj * 16 + arow;
    const float bv = biasp[ocol];
#pragma unroll
    for (int mi = 0; mi < 2; ++mi)
#pragma unroll
      for (int r = 0; r < 4; ++r) {
        const int orow = row0 + wr * 32 + mi * 16 + rgrp + r;
        outp[(long)orow * HDIM + ocol] = acc[mi][nj][r] + bv;
      }
  }
}

// ---------------------------------------------------------------------------
// per-row: inv = 1/sqrt(sum(raw^2)+eps); n2 = sum((raw*inv)^2); bf16 normalized row
__global__ __launch_bounds__(64) void k_rownorm(const float* __restrict__ raw,
                                                float* __restrict__ inv,
                                                float* __restrict__ n2,
                                                unsigned short* __restrict__ nbf) {
  const int row = blockIdx.x;
  const int lane = threadIdx.x;
  const float4 v0 = *(const float4*)&raw[(long)row * HDIM + lane * 8];
  const float4 v1 = *(const float4*)&raw[(long)row * HDIM + lane * 8 + 4];
  float s = v0.x * v0.x + v0.y * v0.y + v0.z * v0.z + v0.w * v0.w
          + v1.x * v1.x + v1.y * v1.y + v1.z * v1.z + v1.w * v1.w;
#pragma unroll
  for (int o = 32; o; o >>= 1) s += __shfl_xor(s, o);
  const float iv = 1.0f / sqrtf(s + 1e-6f);
  float t[8];
  t[0] = v0.x * iv; t[1] = v0.y * iv; t[2] = v0.z * iv; t[3] = v0.w * iv;
  t[4] = v1.x * iv; t[5] = v1.y * iv; t[6] = v1.z * iv; t[7] = v1.w * iv;
  float s2 = 0.0f;
#pragma unroll
  for (int j = 0; j < 8; ++j) s2 += t[j] * t[j];
#pragma unroll
  for (int o = 32; o; o >>= 1) s2 += __shfl_xor(s2, o);
  bf16x8 pk;
#pragma unroll
  for (int j = 0; j < 8; ++j) pk[j] = (short)f2bf(t[j]);
  *(bf16x8*)&nbf[(long)row * HDIM + lane * 8] = pk;
  if (lane == 0) { inv[row] = iv; n2[row] = s2; }
}

// ---------------------------------------------------------------------------
// bf16 MFMA screening: per row, collect candidate codes with ab >= localmax - margin.
__global__ __launch_bounds__(256) void k_dist_screen(const unsigned short* __restrict__ Abf,
                                                     const unsigned short* __restrict__ Bbf,
                                                     int* __restrict__ g_cnt,
                                                     int* __restrict__ g_cand) {
  __shared__ __align__(16) unsigned short A_lds[2][BM][32];
  __shared__ __align__(16) unsigned short B_lds[2][BN][32];

  const int tid = threadIdx.x;
  const int lane = tid & 63;
  const int w = tid >> 6;
  const int wr = w >> 1, wc = w & 1;
  const int row0 = blockIdx.x * BM;
  const int csplit = blockIdx.y * CODES_PER;
  const int wbase = tid & ~63;

  f32x4 acc[2][8];
#pragma unroll
  for (int mi = 0; mi < 2; ++mi)
#pragma unroll
    for (int nj = 0; nj < 8; ++nj)
#pragma unroll
      for (int r = 0; r < 4; ++r) acc[mi][nj][r] = 0.0f;

  float runmax[8];
#pragma unroll
  for (int i = 0; i < 8; ++i) runmax[i] = -3.0e38f;

#define STAGE(s_, b_)                                                              \
  do {                                                                             \
    const int chunk_ = (s_) >> 4, kk_ = (s_) & 15;                                 \
    const long kel_ = (long)(kk_ * 32);                                            \
    {                                                                              \
      const int r_ = tid >> 2, seg_ = tid & 3;                                     \
      const unsigned short* g_ = &Abf[(long)(row0 + r_) * HDIM + kel_ + seg_ * 8]; \
      void* l_ = (char*)&A_lds[b_][0][0] + (size_t)tid * 16;                       \
      gload_lds16(g_, l_);                                                         \
    }                                                                              \
    const int c0_ = csplit + chunk_ * BN;                                          \
    _Pragma("unroll")                                                              \
    for (int i_ = 0; i_ < 4; ++i_) {                                               \
      const int u_ = tid + i_ * 256;                                               \
      const int r_ = u_ >> 2, seg_ = u_ & 3;                                       \
      const unsigned short* g_ = &Bbf[(long)(c0_ + r_) * HDIM + kel_ + seg_ * 8];  \
      void* l_ = (char*)&B_lds[b_][0][0] + (size_t)u_ * 16;                        \
      gload_lds16(g_, l_);                                                         \
    }                                                                              \
  } while (0)

  STAGE(0, 0);
  __syncthreads();

  const int arow = lane & 15;
  const int kcol = (lane >> 4) * 8;
  const int rgrp = (lane >> 4) * 4;

  for (int s = 0; s < NSTEP; ++s) {
    const int b = s & 1;
    if (s + 1 < NSTEP) STAGE(s + 1, b ^ 1);

    bf16x8 af[2], bfr[8];
#pragma unroll
    for (int mi = 0; mi < 2; ++mi)
      af[mi] = *(const bf16x8*)&A_lds[b][wr * 32 + mi * 16 + arow][kcol];
#pragma unroll
    for (int nj = 0; nj < 8; ++nj)
      bfr[nj] = *(const bf16x8*)&B_lds[b][wc * 128 + nj * 16 + arow][kcol];
#pragma unroll
    for (int mi = 0; mi < 2; ++mi)
#pragma unroll
      for (int nj = 0; nj < 8; ++nj)
        acc[mi][nj] = __builtin_amdgcn_mfma_f32_16x16x32_bf16(af[mi], bfr[nj], acc[mi][nj], 0, 0, 0);

    if ((s & 15) == 15) {  // chunk epilogue: screening
      const int chunk = s >> 4;
      const int cbase = csplit + chunk * BN + wc * 128;
      float slotmax[8];
#pragma unroll
      for (int mi = 0; mi < 2; ++mi)
#pragma unroll
        for (int r = 0; r < 4; ++r) {
          float m = acc[mi][0][r];
#pragma unroll
          for (int nj = 1; nj < 8; ++nj) m = fmaxf(m, acc[mi][nj][r]);
          slotmax[mi * 4 + r] = m;
        }
#pragma unroll
      for (int d = 1; d < 16; d <<= 1)
#pragma unroll
        for (int sl = 0; sl < 8; ++sl)
          slotmax[sl] = fmaxf(slotmax[sl], __shfl_xor(slotmax[sl], d));
#pragma unroll
      for (int sl = 0; sl < 8; ++sl) runmax[sl] = fmaxf(runmax[sl], slotmax[sl]);
#pragma unroll
      for (int mi = 0; mi < 2; ++mi)
#pragma unroll
        for (int r = 0; r < 4; ++r) {
          const float th = runmax[mi * 4 + r] - MARGIN_AB;
          const int grow = row0 + wr * 32 + mi * 16 + rgrp + r;
#pragma unroll
          for (int nj = 0; nj < 8; ++nj) {
            const float ab = acc[mi][nj][r];
            if (ab > th) {
              const int c = cbase + nj * 16 + arow;
              const int p = atomicAdd(&g_cnt[grow], 1);
              if (p < CAND_CAP) g_cand[(long)grow * CAND_CAP + p] = c;
            }
            acc[mi][nj][r] = 0.0f;
          }
        }
    }
    __syncthreads();
  }
#undef STAGE
}

// ---------------------------------------------------------------------------
// exact fp32 rescore of candidates; smallest-code tie-break (== first occurrence)
__global__ __launch_bounds__(256) void k_rescore(const float* __restrict__ latin,
                                                 const float* __restrict__ inv_a,
                                                 const float* __restrict__ a2,
                                                 const float* __restrict__ latcb,
                                                 const float* __restrict__ inv_b,
                                                 const float* __restrict__ b2,
                                                 const int* __restrict__ g_cnt,
                                                 const int* __restrict__ g_cand,
                                                 int* __restrict__ idxb,
                                                 float* __restrict__ out_idx,
                                                 int* __restrict__ hist) {
  const int tid = threadIdx.x;
  const int lane = tid & 63;
  const int row = blockIdx.x * 4 + (tid >> 6);
  const float iva = inv_a[row];
  const float4 v0 = *(const float4*)&latin[(long)row * HDIM + lane * 8];
  const float4 v1 = *(const float4*)&latin[(long)row * HDIM + lane * 8 + 4];
  float na[8];
  na[0] = v0.x * iva; na[1] = v0.y * iva; na[2] = v0.z * iva; na[3] = v0.w * iva;
  na[4] = v1.x * iva; na[5] = v1.y * iva; na[6] = v1.z * iva; na[7] = v1.w * iva;
  const float a2r = a2[row];
  int cnt = g_cnt[row]; if (cnt > CAND_CAP) cnt = CAND_CAP;
  float best = 3.4e38f; int bestc = 0x7fffffff;
  for (int ci = 0; ci < cnt; ++ci) {
    const int c = g_cand[(long)row * CAND_CAP + ci];
    const float ivb = inv_b[c];
    const float4 w0 = *(const float4*)&latcb[(long)c * HDIM + lane * 8];
    const float4 w1 = *(const float4*)&latcb[(long)c * HDIM + lane * 8 + 4];
    float dot = 0.0f;
    dot = fmaf(na[0], w0.x * ivb, dot); dot = fmaf(na[1], w0.y * ivb, dot);
    dot = fmaf(na[2], w0.z * ivb, dot); dot = fmaf(na[3], w0.w * ivb, dot);
    dot = fmaf(na[4], w1.x * ivb, dot); dot = fmaf(na[5], w1.y * ivb, dot);
    dot = fmaf(na[6], w1.z * ivb, dot); dot = fmaf(na[7], w1.w * ivb, dot);
#pragma unroll
    for (int o = 32; o; o >>= 1) dot += __shfl_xor(dot, o);
    const float dist = (a2r - 2.0f * dot) + b2[c];
    if (dist < best || (dist == best && c < bestc)) { best = dist; bestc = c; }
  }
  if (lane == 0) {
    idxb[row] = bestc;
    out_idx[row] = (float)bestc;
    atomicAdd(&hist[bestc], 1);
  }
}

// ---------------------------------------------------------------------------
__global__ __launch_bounds__(256) void k_quant_m1(const float* __restrict__ x,
                                                  const float* __restrict__ cb,
                                                  const int* __restrict__ idxb,
                                                  float* __restrict__ outq,
                                                  float* __restrict__ sums) {
  const long u = (long)blockIdx.x * 256 + threadIdx.x;
  const int n = (int)(u / 192);
  const int d = ((int)(u % 192)) * 4;
  const float4 xv = *(const float4*)&x[(long)n * DDIM + d];
  const int k = idxb[n];
  const float4 qv = *(const float4*)&cb[(long)k * DDIM + d];
  const float dx0 = qv.x - xv.x, dx1 = qv.y - xv.y, dx2 = qv.z - xv.z, dx3 = qv.w - xv.w;
  float4 o;
  o.x = xv.x + dx0; o.y = xv.y + dx1; o.z = xv.z + dx2; o.w = xv.w + dx3;
  *(float4*)&outq[(long)n * DDIM + d] = o;
  float lsum = dx0 * dx0 + dx1 * dx1 + dx2 * dx2 + dx3 * dx3;
  __shared__ float red[256];
  const int tid = threadIdx.x;
  red[tid] = lsum; __syncthreads();
  for (int s = 128; s; s >>= 1) { if (tid < s) red[tid] += red[tid + s]; __syncthreads(); }
  if (tid == 0) atomicAdd(&sums[0], red[0]);
}

__global__ __launch_bounds__(256) void k_m2(const float* __restrict__ latin,
                                            const float* __restrict__ latcb,
                                            const int* __restrict__ idxb,
                                            float* __restrict__ sums) {
  const long u = (long)blockIdx.x * 256 + threadIdx.x;
  const int n = (int)(u / 128);
  const int h = ((int)(u % 128)) * 4;
  const int k = idxb[n];
  const float4 lq = *(const float4*)&latcb[(long)k * HDIM + h];
  const float4 lx = *(const float4*)&latin[(long)n * HDIM + h];
  const float d0 = lq.x - lx.x, d1 = lq.y - lx.y, d2 = lq.z - lx.z, d3 = lq.w - lx.w;
  float lsum = d0 * d0 + d1 * d1 + d2 * d2 + d3 * d3;
  __shared__ float red[256];
  const int tid = threadIdx.x;
  red[tid] = lsum; __syncthreads();
  for (int s = 128; s; s >>= 1) { if (tid < s) red[tid] += red[tid + s]; __syncthreads(); }
  if (tid == 0) atomicAdd(&sums[1], red[0]);
}

__global__ __launch_bounds__(256) void k_enc(const int* __restrict__ idxb,
                                             float* __restrict__ enc) {
  const long u = (long)blockIdx.x * 256 + threadIdx.x;
  const int n = (int)(u >> 10);
  const int c0 = ((int)(u & 1023)) << 2;
  const int k = idxb[n];
  float4 e;
  e.x = (c0     == k) ? 1.0f : 0.0f;
  e.y = (c0 + 1 == k) ? 1.0f : 0.0f;
  e.z = (c0 + 2 == k) ? 1.0f : 0.0f;
  e.w = (c0 + 3 == k) ? 1.0f : 0.0f;
  *(float4*)&enc[u << 2] = e;
}

__global__ __launch_bounds__(256) void k_finalize(const int* __restrict__ hist,
                                                  const float* __restrict__ sums,
                                                  float* __restrict__ out) {
  const int tid = threadIdx.x;
  float lsum = 0.0f;
  for (int i = tid; i < KCB; i += 256) {
    const float p = (float)hist[i] * (1.0f / 16384.0f);
    lsum += p * logf(p + 1e-6f);
  }
  __shared__ float red[256];
  red[tid] = lsum; __syncthreads();
  for (int s = 128; s; s >>= 1) { if (tid < s) red[tid] += red[tid + s]; __syncthreads(); }
  if (tid == 0) {
    const float lp = -red[0];
    const float m1 = sums[0] / 12582912.0f;
    const float m2 = sums[1] / 8388608.0f;
    out[LOSS_OFF] = m1 * 1.25f + m2 * 1.25f + 0.1f * lp;
    out[PERP_OFF] = expf(lp);
  }
}

// ---------------------------------------------------------------------------
extern "C" void kernel_launch(void* const* d_in, const int* in_sizes, int n_in,
                              void* d_out, int out_size, void* d_ws, size_t ws_size,
                              hipStream_t stream) {
  const float* x      = (const float*)d_in[0];
  const float* cb     = (const float*)d_in[1];
  const float* w_in   = (const float*)d_in[2];
  const float* b_in   = (const float*)d_in[3];
  const float* w_code = (const float*)d_in[4];
  const float* b_code = (const float*)d_in[5];
  float* out = (float*)d_out;
  char* ws = (char*)d_ws;

  float*          latcb    = (float*)(ws);                      // 8 MB
  float*          latin    = (float*)(ws + 8388608);            // 32 MB
  _Float16*       x2       = (_Float16*)(ws + 41943040);        // 48 MB [hi|lo]
  // x2 region reused after k_hgemm:
  unsigned short* latin_bf = (unsigned short*)(ws + 41943040);  // 16 MB
  unsigned short* latcb_bf = (unsigned short*)(ws + 58720256);  // 4 MB
  int*            g_cand   = (int*)  (ws + 62914560);           // 8 MB
  _Float16*       cb2      = (_Float16*)(ws + 92274688);        // 12 MB
  _Float16*       win2     = (_Float16*)(ws + 104857600);       // 1.5 MB
  _Float16*       wcode2   = (_Float16*)(ws + 106430464);       // 1.5 MB
  float*          inv_b    = (float*)(ws + 108003328);
  float*          b2       = (float*)(ws + 108019712);
  float*          inv_a    = (float*)(ws + 108036096);
  float*          a2       = (float*)(ws + 108101632);
  int*            idxb     = (int*)  (ws + 108167168);
  int*            hist     = (int*)  (ws + 108232704);
  float*          sums     = (float*)(ws + 108249088);
  int*            g_cnt    = (int*)  (ws + 108249120);

  k_init<<<64, 256, 0, stream>>>(hist, sums, g_cnt);
  k_split<<<(N_TOK * 96) / 256, 256, 0, stream>>>(x, x2);
  k_split<<<(KCB * 96) / 256,   256, 0, stream>>>(cb, cb2);
  k_split<<<(HDIM * 96) / 256,  256, 0, stream>>>(w_in, win2);
  k_split<<<(HDIM * 96) / 256,  256, 0, stream>>>(w_code, wcode2);
  k_hgemm<<<dim3(256 + KCB / BM, HDIM / BN), 256, 0, stream>>>(x2, cb2, win2, wcode2,
                                                               b_in, b_code, latin, latcb);
  k_rownorm<<<KCB,   64, 0, stream>>>(latcb, inv_b, b2, latcb_bf);
  k_rownorm<<<N_TOK, 64, 0, stream>>>(latin, inv_a, a2, latin_bf);
  k_dist_screen<<<dim3(N_TOK / BM, NSPLIT), 256, 0, stream>>>(latin_bf, latcb_bf, g_cnt, g_cand);
  k_rescore<<<N_TOK / 4, 256, 0, stream>>>(latin, inv_a, a2, latcb, inv_b, b2,
                                           g_cnt, g_cand, idxb, out + IDX_OFF, hist);
  k_quant_m1<<<(N_TOK * (DDIM / 4)) / 256, 256, 0, stream>>>(x, cb, idxb, out + Q_OFF, sums);
  k_m2<<<(N_TOK * (HDIM / 4)) / 256, 256, 0, stream>>>(latin, latcb, idxb, sums);
  k_enc<<<(N_TOK * (KCB / 4)) / 256, 256, 0, stream>>>(idxb, out + ENC_OFF);
  k_finalize<<<1, 256, 0, stream>>>(hist, sums, out);
}